// Round 1
// baseline (121.178 us; speedup 1.0000x reference)
//
#include <hip/hip_runtime.h>
#include <math.h>

// Lorenz Lyapunov-exponent integrator — round 6.
// R5 post-mortem (cycle arithmetic): f2 did NOT compile to packed fp32 —
// measured 40.7 µs @ 63% busy matches the UNPACKED issue count (58.8k
// issue-cycles/SIMD), not the packed one (29.4k). So vector width never
// reduced instruction count; it only cost TLP. Total VALU work is fixed
// => maximize issue-slot utilization: 1 trajectory/thread, 262144 threads,
// 4 waves/SIMD (R1 showed ~90% busy at this occupancy). Same R4 compute
// structure: GS every K=20 steps, telescoped log-norms, no per-step
// transcendentals. Math is elementwise-identical to R5 (same op order).

#define SIGMA 10.0f
#define RHO   28.0f
#define DT    0.01f
#define BETA  (8.0f / 3.0f)
#define LN2_HALF 0.34657359027997264f   // 0.5 * ln(2)
#define GS_K 20

#pragma clang fp contract(fast)

__device__ __forceinline__ void lorenz_f(float X, float Y, float Z,
                                         float& fx, float& fy, float& fz) {
    fx = SIGMA * (Y - X);
    fy = X * (RHO - Z) - Y;
    fz = X * Y - BETA * Z;
}

struct State {
    float X, Y, Z;
    float q00, q01, q02, q10, q11, q12, q20, q21, q22;
};

__device__ __forceinline__ void rk4_jq_step(State& s) {
    // ---- RK4 step (reference quirk: k4 uses k2, not k3) ----
    float k1x, k1y, k1z, k2x, k2y, k2z, k3x, k3y, k3z, k4x, k4y, k4z;
    lorenz_f(s.X, s.Y, s.Z, k1x, k1y, k1z);
    lorenz_f(s.X + (DT * 0.5f) * k1x, s.Y + (DT * 0.5f) * k1y, s.Z + (DT * 0.5f) * k1z,
             k2x, k2y, k2z);
    lorenz_f(s.X + (DT * 0.5f) * k2x, s.Y + (DT * 0.5f) * k2y, s.Z + (DT * 0.5f) * k2z,
             k3x, k3y, k3z);
    lorenz_f(s.X + DT * k2x, s.Y + DT * k2y, s.Z + DT * k2z,   // (sic) k2
             k4x, k4y, k4z);
    s.X = s.X + DT * (k1x + 2.0f * k2x + 2.0f * k3x + k4x) * (1.0f / 6.0f);
    s.Y = s.Y + DT * (k1y + 2.0f * k2y + 2.0f * k3y + k4y) * (1.0f / 6.0f);
    s.Z = s.Z + DT * (k1z + 2.0f * k2z + 2.0f * k3z + k4z) * (1.0f / 6.0f);

    // ---- Tangent map J = I + DT*Df at the NEW x (j02 == 0) ----
    const float j10 = DT * (RHO - s.Z);
    const float j12 = -DT * s.X;
    const float j20 = DT * s.Y;
    const float j21 = DT * s.X;
    const float j00 = 1.0f - DT * SIGMA;
    const float j01 = DT * SIGMA;
    const float j11 = 1.0f - DT;
    const float j22 = 1.0f - DT * BETA;

    // ---- Q = J @ Q ----
    float n00 = j00 * s.q00 + j01 * s.q10;
    float n01 = j00 * s.q01 + j01 * s.q11;
    float n02 = j00 * s.q02 + j01 * s.q12;
    float n10 = j10 * s.q00 + j11 * s.q10 + j12 * s.q20;
    float n11 = j10 * s.q01 + j11 * s.q11 + j12 * s.q21;
    float n12 = j10 * s.q02 + j11 * s.q12 + j12 * s.q22;
    float n20 = j20 * s.q00 + j21 * s.q10 + j22 * s.q20;
    float n21 = j20 * s.q01 + j21 * s.q11 + j22 * s.q21;
    float n22 = j20 * s.q02 + j21 * s.q12 + j22 * s.q22;
    s.q00 = n00; s.q01 = n01; s.q02 = n02;
    s.q10 = n10; s.q11 = n11; s.q12 = n12;
    s.q20 = n20; s.q21 = n21; s.q22 = n22;
}

__device__ __forceinline__ void gram_schmidt(State& s) {
    // Classical GS, unnormalized, projection coeffs from ORIGINAL columns.
    float ib0 = s.q00 * s.q00 + s.q10 * s.q10 + s.q20 * s.q20;
    float rib0 = __builtin_amdgcn_rcpf(ib0);

    float d01 = s.q00 * s.q01 + s.q10 * s.q11 + s.q20 * s.q21;
    float c1 = d01 * rib0;
    float b10 = s.q01 - c1 * s.q00;
    float b11 = s.q11 - c1 * s.q10;
    float b12 = s.q21 - c1 * s.q20;

    float d02 = s.q00 * s.q02 + s.q10 * s.q12 + s.q20 * s.q22;
    float c2 = d02 * rib0;
    float e0 = s.q02 - c2 * s.q00;
    float e1 = s.q12 - c2 * s.q10;
    float e2 = s.q22 - c2 * s.q20;
    float ib1 = b10 * b10 + b11 * b11 + b12 * b12;
    float d12 = b10 * s.q02 + b11 * s.q12 + b12 * s.q22;
    float c3 = d12 * __builtin_amdgcn_rcpf(ib1);
    s.q02 = e0 - c3 * b10;
    s.q12 = e1 - c3 * b11;
    s.q22 = e2 - c3 * b12;
    s.q01 = b10; s.q11 = b11; s.q21 = b12;
}

__global__ __launch_bounds__(256, 4)
void lorenz_lya_kernel(const float* __restrict__ x0,
                       const float* __restrict__ ts,
                       float* __restrict__ out,
                       int B, int T) {
    int i = blockIdx.x * blockDim.x + threadIdx.x;
    if (i >= B) return;

    State s;
    s.X = x0[0 * B + i];
    s.Y = x0[1 * B + i];
    s.Z = x0[2 * B + i];
    s.q00 = 1.0f; s.q01 = 0.0f; s.q02 = 0.0f;
    s.q10 = 0.0f; s.q11 = 1.0f; s.q12 = 0.0f;
    s.q20 = 0.0f; s.q21 = 0.0f; s.q22 = 1.0f;

    float t_last = ts[T - 1];

    int it = 0;
    while (it < T) {
        int kend = T - it;
        if (kend >= GS_K) {
            #pragma unroll 5
            for (int u = 0; u < GS_K; ++u) rk4_jq_step(s);
            it += GS_K;
        } else {
            for (int u = 0; u < kend; ++u) rk4_jq_step(s);
            it += kend;
        }
        gram_schmidt(s);
    }

    // Final column norms^2; lya_j = 0.5*ln2*log2(ib_j) / (t_last + DT)
    float ib0 = s.q00 * s.q00 + s.q10 * s.q10 + s.q20 * s.q20;
    float ib1 = s.q01 * s.q01 + s.q11 * s.q11 + s.q21 * s.q21;
    float ib2 = s.q02 * s.q02 + s.q12 * s.q12 + s.q22 * s.q22;

    float scale = LN2_HALF * __builtin_amdgcn_rcpf(t_last + DT);
    out[0 * B + i] = __builtin_amdgcn_logf(ib0) * scale;
    out[1 * B + i] = __builtin_amdgcn_logf(ib1) * scale;
    out[2 * B + i] = __builtin_amdgcn_logf(ib2) * scale;
    out[3 * B + i] = s.X;
    out[4 * B + i] = s.Y;
    out[5 * B + i] = s.Z;
}

extern "C" void kernel_launch(void* const* d_in, const int* in_sizes, int n_in,
                              void* d_out, int out_size, void* d_ws, size_t ws_size,
                              hipStream_t stream) {
    const float* x0 = (const float*)d_in[0];
    const float* ts = (const float*)d_in[1];
    float* out = (float*)d_out;
    int B = in_sizes[0] / 3;
    int T = in_sizes[1];
    int threads = 256;
    int blocks = (B + threads - 1) / threads;
    lorenz_lya_kernel<<<blocks, threads, 0, stream>>>(x0, ts, out, B, T);
}

// Round 2
// 87.912 us; speedup vs baseline: 1.3784x; 1.3784x over previous
//
#include <hip/hip_runtime.h>
#include <math.h>

// Lorenz Lyapunov-exponent integrator — round 7.
// R6 post-mortem: scalar@4waves = 78 µs @ 82% busy vs f2@2waves = 40.7 µs
// @ 63% busy => f2 WAS packing (v_pk_*_f32). Busy-cycle arithmetic:
// R5's 61.5k busy-cycles/SIMD == the packed-fp32 pipe floor (64k @ 4
// cyc/pk-instr), so R5's pipe was active exactly as long as physics
// requires; the 37% idle is a FEEDING problem. Explicit parallelism is
// capped at 2 chains/SIMD (131072 pairs / 1024 SIMDs), so the extra ILP
// must come from within a step: J(t)@Q is independent of RK4(t+1) (both
// need only x(t)). This version software-pipelines the Q-update one step
// behind the RK4 integration and interleaves the two at source level in
// one scheduling region. Ops are identical to R5, just deferred.

#define SIGMA 10.0f
#define RHO   28.0f
#define DT    0.01f
#define BETA  (8.0f / 3.0f)
#define LN2_HALF 0.34657359027997264f   // 0.5 * ln(2)
#define GS_K 20

#pragma clang fp contract(fast)

typedef float f2 __attribute__((ext_vector_type(2)));

__device__ __forceinline__ f2 rcp2(f2 a) {
    f2 r;
    r.x = __builtin_amdgcn_rcpf(a.x);
    r.y = __builtin_amdgcn_rcpf(a.y);
    return r;
}
__device__ __forceinline__ f2 log2_2(f2 a) {
    f2 r;
    r.x = __builtin_amdgcn_logf(a.x);
    r.y = __builtin_amdgcn_logf(a.y);
    return r;
}

__device__ __forceinline__ void lorenz_f(f2 X, f2 Y, f2 Z, f2& fx, f2& fy, f2& fz) {
    fx = SIGMA * (Y - X);
    fy = X * (RHO - Z) - Y;
    fz = X * Y - BETA * Z;
}

struct State {
    f2 X, Y, Z;
    f2 q00, q01, q02, q10, q11, q12, q20, q21, q22;
};

// Pending tangent map from the previous step (variable entries only).
struct J2 {
    f2 j10, j12, j20, j21;
};

// Constant J entries.
#define J00 (1.0f - DT * SIGMA)
#define J01 (DT * SIGMA)
#define J11 (1.0f - DT)
#define J22 (1.0f - DT * BETA)

// RK4 advance of x only; emits J at the NEW x into jn.
__device__ __forceinline__ void rk4_advance(State& s, J2& jn) {
    f2 k1x, k1y, k1z, k2x, k2y, k2z, k3x, k3y, k3z, k4x, k4y, k4z;
    lorenz_f(s.X, s.Y, s.Z, k1x, k1y, k1z);
    lorenz_f(s.X + (DT * 0.5f) * k1x, s.Y + (DT * 0.5f) * k1y, s.Z + (DT * 0.5f) * k1z,
             k2x, k2y, k2z);
    lorenz_f(s.X + (DT * 0.5f) * k2x, s.Y + (DT * 0.5f) * k2y, s.Z + (DT * 0.5f) * k2z,
             k3x, k3y, k3z);
    lorenz_f(s.X + DT * k2x, s.Y + DT * k2y, s.Z + DT * k2z,   // (sic) k2 — reference quirk
             k4x, k4y, k4z);
    s.X = s.X + DT * (k1x + 2.0f * k2x + 2.0f * k3x + k4x) * (1.0f / 6.0f);
    s.Y = s.Y + DT * (k1y + 2.0f * k2y + 2.0f * k3y + k4y) * (1.0f / 6.0f);
    s.Z = s.Z + DT * (k1z + 2.0f * k2z + 2.0f * k3z + k4z) * (1.0f / 6.0f);
    jn.j10 = DT * (RHO - s.Z);
    jn.j12 = -DT * s.X;
    jn.j20 = DT * s.Y;
    jn.j21 = DT * s.X;
}

// Q = J @ Q for a given (pending) J.
__device__ __forceinline__ void apply_JQ(State& s, const J2& j) {
    f2 n00 = J00 * s.q00 + J01 * s.q10;
    f2 n01 = J00 * s.q01 + J01 * s.q11;
    f2 n02 = J00 * s.q02 + J01 * s.q12;
    f2 n10 = j.j10 * s.q00 + J11 * s.q10 + j.j12 * s.q20;
    f2 n11 = j.j10 * s.q01 + J11 * s.q11 + j.j12 * s.q21;
    f2 n12 = j.j10 * s.q02 + J11 * s.q12 + j.j12 * s.q22;
    f2 n20 = j.j20 * s.q00 + j.j21 * s.q10 + J22 * s.q20;
    f2 n21 = j.j20 * s.q01 + j.j21 * s.q11 + J22 * s.q21;
    f2 n22 = j.j20 * s.q02 + j.j21 * s.q12 + J22 * s.q22;
    s.q00 = n00; s.q01 = n01; s.q02 = n02;
    s.q10 = n10; s.q11 = n11; s.q12 = n12;
    s.q20 = n20; s.q21 = n21; s.q22 = n22;
}

// One pipelined step: RK4 advance x (t -> t+1) interleaved with the
// Q-update for the PREVIOUS step's J (held in j). On exit j = J(x_{t+1}).
// The Q-dot groups are mutually independent of the RK4 serial chain —
// co-locating them gives the scheduler independent work to slot into the
// dependent-FMA latency gaps.
__device__ __forceinline__ void fused_step(State& s, J2& j) {
    f2 k1x, k1y, k1z, k2x, k2y, k2z, k3x, k3y, k3z, k4x, k4y, k4z;

    // RK4 stage 1
    lorenz_f(s.X, s.Y, s.Z, k1x, k1y, k1z);
    // Q row 0 (constants only — fully independent)
    f2 n00 = J00 * s.q00 + J01 * s.q10;
    f2 n01 = J00 * s.q01 + J01 * s.q11;
    f2 n02 = J00 * s.q02 + J01 * s.q12;

    // RK4 stage 2
    lorenz_f(s.X + (DT * 0.5f) * k1x, s.Y + (DT * 0.5f) * k1y, s.Z + (DT * 0.5f) * k1z,
             k2x, k2y, k2z);
    // Q row 1 (uses pending j — independent of RK4 chain)
    f2 n10 = j.j10 * s.q00 + J11 * s.q10 + j.j12 * s.q20;
    f2 n11 = j.j10 * s.q01 + J11 * s.q11 + j.j12 * s.q21;
    f2 n12 = j.j10 * s.q02 + J11 * s.q12 + j.j12 * s.q22;

    // RK4 stage 3
    lorenz_f(s.X + (DT * 0.5f) * k2x, s.Y + (DT * 0.5f) * k2y, s.Z + (DT * 0.5f) * k2z,
             k3x, k3y, k3z);
    // Q row 2
    f2 n20 = j.j20 * s.q00 + j.j21 * s.q10 + J22 * s.q20;
    f2 n21 = j.j20 * s.q01 + j.j21 * s.q11 + J22 * s.q21;
    f2 n22 = j.j20 * s.q02 + j.j21 * s.q12 + J22 * s.q22;

    // RK4 stage 4 (uses k2 — reference quirk)
    lorenz_f(s.X + DT * k2x, s.Y + DT * k2y, s.Z + DT * k2z,
             k4x, k4y, k4z);
    // Commit Q
    s.q00 = n00; s.q01 = n01; s.q02 = n02;
    s.q10 = n10; s.q11 = n11; s.q12 = n12;
    s.q20 = n20; s.q21 = n21; s.q22 = n22;

    // Combine x
    s.X = s.X + DT * (k1x + 2.0f * k2x + 2.0f * k3x + k4x) * (1.0f / 6.0f);
    s.Y = s.Y + DT * (k1y + 2.0f * k2y + 2.0f * k3y + k4y) * (1.0f / 6.0f);
    s.Z = s.Z + DT * (k1z + 2.0f * k2z + 2.0f * k3z + k4z) * (1.0f / 6.0f);

    // New pending J at the new x
    j.j10 = DT * (RHO - s.Z);
    j.j12 = -DT * s.X;
    j.j20 = DT * s.Y;
    j.j21 = DT * s.X;
}

__device__ __forceinline__ void gram_schmidt(State& s) {
    // Classical GS, unnormalized, projection coeffs from ORIGINAL columns.
    f2 ib0 = s.q00 * s.q00 + s.q10 * s.q10 + s.q20 * s.q20;
    f2 rib0 = rcp2(ib0);

    f2 d01 = s.q00 * s.q01 + s.q10 * s.q11 + s.q20 * s.q21;
    f2 c1 = d01 * rib0;
    f2 b10 = s.q01 - c1 * s.q00;
    f2 b11 = s.q11 - c1 * s.q10;
    f2 b12 = s.q21 - c1 * s.q20;

    f2 d02 = s.q00 * s.q02 + s.q10 * s.q12 + s.q20 * s.q22;
    f2 c2 = d02 * rib0;
    f2 e0 = s.q02 - c2 * s.q00;
    f2 e1 = s.q12 - c2 * s.q10;
    f2 e2 = s.q22 - c2 * s.q20;
    f2 ib1 = b10 * b10 + b11 * b11 + b12 * b12;
    f2 d12 = b10 * s.q02 + b11 * s.q12 + b12 * s.q22;
    f2 c3 = d12 * rcp2(ib1);
    s.q02 = e0 - c3 * b10;
    s.q12 = e1 - c3 * b11;
    s.q22 = e2 - c3 * b12;
    s.q01 = b10; s.q11 = b11; s.q21 = b12;
}

__global__ __launch_bounds__(256, 2)
void lorenz_lya_kernel(const float* __restrict__ x0,
                       const float* __restrict__ ts,
                       float* __restrict__ out,
                       int B, int T) {
    int p = blockIdx.x * blockDim.x + threadIdx.x;   // pair index
    int Bh = B >> 1;
    if (p >= Bh) return;

    const f2* x0v = (const f2*)x0;
    f2* outv = (f2*)out;

    State s;
    s.X = x0v[0 * Bh + p];
    s.Y = x0v[1 * Bh + p];
    s.Z = x0v[2 * Bh + p];
    s.q00 = 1.0f; s.q01 = 0.0f; s.q02 = 0.0f;
    s.q10 = 0.0f; s.q11 = 1.0f; s.q12 = 0.0f;
    s.q20 = 0.0f; s.q21 = 0.0f; s.q22 = 1.0f;

    float t_last = ts[T - 1];

    int it = 0;
    while (it < T) {
        int kend = T - it;
        if (kend > GS_K) kend = GS_K;
        J2 j;
        if (kend == GS_K) {
            rk4_advance(s, j);          // step 1 of segment: no pending J
            #pragma unroll 2
            for (int u = 1; u < GS_K; ++u) fused_step(s, j);
        } else {
            rk4_advance(s, j);
            for (int u = 1; u < kend; ++u) fused_step(s, j);
        }
        apply_JQ(s, j);                 // flush pending J before GS
        gram_schmidt(s);
        it += kend;
    }

    // Final column norms^2; lya_j = 0.5*ln2*log2(ib_j) / (t_last + DT)
    f2 ib0 = s.q00 * s.q00 + s.q10 * s.q10 + s.q20 * s.q20;
    f2 ib1 = s.q01 * s.q01 + s.q11 * s.q11 + s.q21 * s.q21;
    f2 ib2 = s.q02 * s.q02 + s.q12 * s.q12 + s.q22 * s.q22;

    float scale = LN2_HALF * __builtin_amdgcn_rcpf(t_last + DT);
    outv[0 * Bh + p] = log2_2(ib0) * scale;
    outv[1 * Bh + p] = log2_2(ib1) * scale;
    outv[2 * Bh + p] = log2_2(ib2) * scale;
    outv[3 * Bh + p] = s.X;
    outv[4 * Bh + p] = s.Y;
    outv[5 * Bh + p] = s.Z;
}

extern "C" void kernel_launch(void* const* d_in, const int* in_sizes, int n_in,
                              void* d_out, int out_size, void* d_ws, size_t ws_size,
                              hipStream_t stream) {
    const float* x0 = (const float*)d_in[0];
    const float* ts = (const float*)d_in[1];
    float* out = (float*)d_out;
    int B = in_sizes[0] / 3;
    int T = in_sizes[1];
    int threads = 256;
    int pairs = B / 2;
    int blocks = (pairs + threads - 1) / threads;
    lorenz_lya_kernel<<<blocks, threads, 0, stream>>>(x0, ts, out, B, T);
}

// Round 3
// 85.403 us; speedup vs baseline: 1.4189x; 1.0294x over previous
//
#include <hip/hip_runtime.h>
#include <math.h>

// Lorenz Lyapunov-exponent integrator — round 8.
// R7 post-mortem: source-order interleave was a no-op (41.2µs vs 40.7µs)
// — the scheduler re-sorts the region into serialized chains (duty 63%,
// effective dependent spacing L~12.7cyc, busy-cycles == the 61.5k packed-
// pipe floor exactly). Fix: pin a chain-interleaved order with
// __builtin_amdgcn_sched_barrier(0) fences between 3-op chunks
// (RK4 x/y/z triples alternating with Q-dot triples). No memory ops in
// the loop body, so the m141 waitcnt-poisoning failure mode can't occur.
// Also: j12 == -j21 exploited (free VOP3 neg modifier), one op/step saved.

#define SIGMA 10.0f
#define RHO   28.0f
#define DT    0.01f
#define BETA  (8.0f / 3.0f)
#define LN2_HALF 0.34657359027997264f   // 0.5 * ln(2)
#define GS_K 20

#pragma clang fp contract(fast)

#define SB() __builtin_amdgcn_sched_barrier(0)

typedef float f2 __attribute__((ext_vector_type(2)));

__device__ __forceinline__ f2 rcp2(f2 a) {
    f2 r;
    r.x = __builtin_amdgcn_rcpf(a.x);
    r.y = __builtin_amdgcn_rcpf(a.y);
    return r;
}
__device__ __forceinline__ f2 log2_2(f2 a) {
    f2 r;
    r.x = __builtin_amdgcn_logf(a.x);
    r.y = __builtin_amdgcn_logf(a.y);
    return r;
}

__device__ __forceinline__ void lorenz_f(f2 X, f2 Y, f2 Z, f2& fx, f2& fy, f2& fz) {
    fx = SIGMA * (Y - X);
    fy = X * (RHO - Z) - Y;
    fz = X * Y - BETA * Z;
}

struct State {
    f2 X, Y, Z;
    f2 q00, q01, q02, q10, q11, q12_unused, q20, q21, q22;
};

// Pending tangent map entries (j12 == -j21, not stored).
struct J2 {
    f2 j10, j20, j21;
};

// Constant J entries.
#define J00 (1.0f - DT * SIGMA)
#define J01 (DT * SIGMA)
#define J11 (1.0f - DT)
#define J22 (1.0f - DT * BETA)

// Plain RK4 advance of x; emits J at the NEW x into jn. (Used once per
// GS segment where there is no pending J — not on the hot path.)
__device__ __forceinline__ void rk4_advance(State& s, J2& jn) {
    f2 k1x, k1y, k1z, k2x, k2y, k2z, k3x, k3y, k3z, k4x, k4y, k4z;
    lorenz_f(s.X, s.Y, s.Z, k1x, k1y, k1z);
    lorenz_f(s.X + (DT * 0.5f) * k1x, s.Y + (DT * 0.5f) * k1y, s.Z + (DT * 0.5f) * k1z,
             k2x, k2y, k2z);
    lorenz_f(s.X + (DT * 0.5f) * k2x, s.Y + (DT * 0.5f) * k2y, s.Z + (DT * 0.5f) * k2z,
             k3x, k3y, k3z);
    lorenz_f(s.X + DT * k2x, s.Y + DT * k2y, s.Z + DT * k2z,   // (sic) k2 — reference quirk
             k4x, k4y, k4z);
    s.X = s.X + DT * (k1x + 2.0f * k2x + 2.0f * k3x + k4x) * (1.0f / 6.0f);
    s.Y = s.Y + DT * (k1y + 2.0f * k2y + 2.0f * k3y + k4y) * (1.0f / 6.0f);
    s.Z = s.Z + DT * (k1z + 2.0f * k2z + 2.0f * k3z + k4z) * (1.0f / 6.0f);
    jn.j10 = DT * (RHO - s.Z);
    jn.j20 = DT * s.Y;
    jn.j21 = DT * s.X;
}

// Q = J @ Q for a pending J (flush before GS).  j12 = -j21.
__device__ __forceinline__ void apply_JQ(State& s, const J2& j) {
    f2 n00 = J00 * s.q00 + J01 * s.q10;
    f2 n01 = J00 * s.q01 + J01 * s.q11;
    f2 n02 = J00 * s.q02 + J01 * s.q12_unused; // see note: q12 slot holds col2 row1
    // (naming kept from earlier rounds; q12_unused IS the live q12 entry)
    f2 n10 = j.j10 * s.q00 + J11 * s.q10 - j.j21 * s.q20;
    f2 n11 = j.j10 * s.q01 + J11 * s.q11 - j.j21 * s.q21;
    f2 n12 = j.j10 * s.q02 + J11 * s.q12_unused - j.j21 * s.q22;
    f2 n20 = j.j20 * s.q00 + j.j21 * s.q10 + J22 * s.q20;
    f2 n21 = j.j20 * s.q01 + j.j21 * s.q11 + J22 * s.q21;
    f2 n22 = j.j20 * s.q02 + j.j21 * s.q12_unused + J22 * s.q22;
    s.q00 = n00; s.q01 = n01; s.q02 = n02;
    s.q10 = n10; s.q11 = n11; s.q12_unused = n12;
    s.q20 = n20; s.q21 = n21; s.q22 = n22;
}

// One pipelined step with a PINNED chain-interleaved schedule.
// A-chain: RK4 for step t+1.  B-chain: Q <- J(t) @ Q (independent of A).
// sched_barrier(0) between chunks stops the scheduler from re-serializing.
__device__ __forceinline__ void fused_step(State& s, J2& j) {
    // [1] A: stage-1 preamble
    f2 u1 = s.Y - s.X;
    f2 v1 = RHO - s.Z;
    f2 w1 = BETA * s.Z;
    SB();
    // [2] B: row0 muls
    f2 m00 = J00 * s.q00;
    f2 m01 = J00 * s.q01;
    f2 m02 = J00 * s.q02;
    SB();
    // [3] A: k1
    f2 k1x = SIGMA * u1;
    f2 k1y = s.X * v1 - s.Y;
    f2 k1z = s.X * s.Y - w1;
    SB();
    // [4] B: row0 fmas
    f2 n00 = m00 + J01 * s.q10;
    f2 n01 = m01 + J01 * s.q11;
    f2 n02 = m02 + J01 * s.q12_unused;
    SB();
    // [5] A: stage-2 args
    f2 ax = s.X + (DT * 0.5f) * k1x;
    f2 ay = s.Y + (DT * 0.5f) * k1y;
    f2 az = s.Z + (DT * 0.5f) * k1z;
    SB();
    // [6] B: row1 muls
    f2 p10 = j.j10 * s.q00;
    f2 p11 = j.j10 * s.q01;
    f2 p12 = j.j10 * s.q02;
    SB();
    // [7] A: stage-2 preamble
    f2 u2 = ay - ax;
    f2 v2 = RHO - az;
    f2 w2 = BETA * az;
    SB();
    // [8] B: row1 += J11*q1k
    p10 = p10 + J11 * s.q10;
    p11 = p11 + J11 * s.q11;
    p12 = p12 + J11 * s.q12_unused;
    SB();
    // [9] A: k2
    f2 k2x = SIGMA * u2;
    f2 k2y = ax * v2 - ay;
    f2 k2z = ax * ay - w2;
    SB();
    // [10] B: row1 finish (j12 = -j21)
    f2 n10 = p10 - j.j21 * s.q20;
    f2 n11 = p11 - j.j21 * s.q21;
    f2 n12 = p12 - j.j21 * s.q22;
    SB();
    // [11] A: stage-3 args
    f2 bx = s.X + (DT * 0.5f) * k2x;
    f2 by = s.Y + (DT * 0.5f) * k2y;
    f2 bz = s.Z + (DT * 0.5f) * k2z;
    SB();
    // [12] B: row2 muls
    f2 p20 = j.j20 * s.q00;
    f2 p21 = j.j20 * s.q01;
    f2 p22 = j.j20 * s.q02;
    SB();
    // [13] A: stage-3 preamble
    f2 u3 = by - bx;
    f2 v3 = RHO - bz;
    f2 w3 = BETA * bz;
    SB();
    // [14] B: row2 += j21*q1k
    p20 = p20 + j.j21 * s.q10;
    p21 = p21 + j.j21 * s.q11;
    p22 = p22 + j.j21 * s.q12_unused;
    SB();
    // [15] A: k3
    f2 k3x = SIGMA * u3;
    f2 k3y = bx * v3 - by;
    f2 k3z = bx * by - w3;
    SB();
    // [16] B: row2 finish
    f2 n20 = p20 + J22 * s.q20;
    f2 n21 = p21 + J22 * s.q21;
    f2 n22 = p22 + J22 * s.q22;
    SB();
    // [17] A: stage-4 args (k4 uses k2 — reference quirk)
    f2 cx = s.X + DT * k2x;
    f2 cy = s.Y + DT * k2y;
    f2 cz = s.Z + DT * k2z;
    SB();
    // [18] A: combine part 1 (independent of k3/k4)
    f2 sx = k1x + 2.0f * k2x;
    f2 sy = k1y + 2.0f * k2y;
    f2 sz = k1z + 2.0f * k2z;
    SB();
    // [19] A: stage-4 preamble
    f2 u4 = cy - cx;
    f2 v4 = RHO - cz;
    f2 w4 = BETA * cz;
    SB();
    // [20] A: combine part 2
    sx = sx + 2.0f * k3x;
    sy = sy + 2.0f * k3y;
    sz = sz + 2.0f * k3z;
    SB();
    // [21] A: k4
    f2 k4x = SIGMA * u4;
    f2 k4y = cx * v4 - cy;
    f2 k4z = cx * cy - w4;
    SB();
    // [22] commit Q (register renames) + combine part 3
    s.q00 = n00; s.q01 = n01; s.q02 = n02;
    s.q10 = n10; s.q11 = n11; s.q12_unused = n12;
    s.q20 = n20; s.q21 = n21; s.q22 = n22;
    sx = sx + k4x;
    sy = sy + k4y;
    sz = sz + k4z;
    SB();
    // [23] A: x update
    s.X = s.X + DT * sx * (1.0f / 6.0f);
    s.Y = s.Y + DT * sy * (1.0f / 6.0f);
    s.Z = s.Z + DT * sz * (1.0f / 6.0f);
    SB();
    // [24] A: new pending J
    j.j10 = DT * (RHO - s.Z);
    j.j20 = DT * s.Y;
    j.j21 = DT * s.X;
    SB();
}

__device__ __forceinline__ void gram_schmidt(State& s) {
    // Classical GS, unnormalized, projection coeffs from ORIGINAL columns.
    f2 ib0 = s.q00 * s.q00 + s.q10 * s.q10 + s.q20 * s.q20;
    f2 rib0 = rcp2(ib0);

    f2 d01 = s.q00 * s.q01 + s.q10 * s.q11 + s.q20 * s.q21;
    f2 c1 = d01 * rib0;
    f2 b10 = s.q01 - c1 * s.q00;
    f2 b11 = s.q11 - c1 * s.q10;
    f2 b12 = s.q21 - c1 * s.q20;

    f2 d02 = s.q00 * s.q02 + s.q10 * s.q12_unused + s.q20 * s.q22;
    f2 c2 = d02 * rib0;
    f2 e0 = s.q02 - c2 * s.q00;
    f2 e1 = s.q12_unused - c2 * s.q10;
    f2 e2 = s.q22 - c2 * s.q20;
    f2 ib1 = b10 * b10 + b11 * b11 + b12 * b12;
    f2 d12 = b10 * s.q02 + b11 * s.q12_unused + b12 * s.q22;
    f2 c3 = d12 * rcp2(ib1);
    s.q02 = e0 - c3 * b10;
    s.q12_unused = e1 - c3 * b11;
    s.q22 = e2 - c3 * b12;
    s.q01 = b10; s.q11 = b11; s.q21 = b12;
}

__global__ __launch_bounds__(256, 2)
void lorenz_lya_kernel(const float* __restrict__ x0,
                       const float* __restrict__ ts,
                       float* __restrict__ out,
                       int B, int T) {
    int p = blockIdx.x * blockDim.x + threadIdx.x;   // pair index
    int Bh = B >> 1;
    if (p >= Bh) return;

    const f2* x0v = (const f2*)x0;
    f2* outv = (f2*)out;

    State s;
    s.X = x0v[0 * Bh + p];
    s.Y = x0v[1 * Bh + p];
    s.Z = x0v[2 * Bh + p];
    s.q00 = 1.0f; s.q01 = 0.0f; s.q02 = 0.0f;
    s.q10 = 0.0f; s.q11 = 1.0f; s.q12_unused = 0.0f;
    s.q20 = 0.0f; s.q21 = 0.0f; s.q22 = 1.0f;

    float t_last = ts[T - 1];

    int it = 0;
    while (it < T) {
        int kend = T - it;
        if (kend > GS_K) kend = GS_K;
        J2 j;
        if (kend == GS_K) {
            rk4_advance(s, j);          // segment head: no pending J
            #pragma unroll 2
            for (int u = 1; u < GS_K; ++u) fused_step(s, j);
        } else {
            rk4_advance(s, j);
            for (int u = 1; u < kend; ++u) fused_step(s, j);
        }
        apply_JQ(s, j);                 // flush pending J before GS
        gram_schmidt(s);
        it += kend;
    }

    // Final column norms^2; lya_j = 0.5*ln2*log2(ib_j) / (t_last + DT)
    f2 ib0 = s.q00 * s.q00 + s.q10 * s.q10 + s.q20 * s.q20;
    f2 ib1 = s.q01 * s.q01 + s.q11 * s.q11 + s.q21 * s.q21;
    f2 ib2 = s.q02 * s.q02 + s.q12_unused * s.q12_unused + s.q22 * s.q22;

    float scale = LN2_HALF * __builtin_amdgcn_rcpf(t_last + DT);
    outv[0 * Bh + p] = log2_2(ib0) * scale;
    outv[1 * Bh + p] = log2_2(ib1) * scale;
    outv[2 * Bh + p] = log2_2(ib2) * scale;
    outv[3 * Bh + p] = s.X;
    outv[4 * Bh + p] = s.Y;
    outv[5 * Bh + p] = s.Z;
}

extern "C" void kernel_launch(void* const* d_in, const int* in_sizes, int n_in,
                              void* d_out, int out_size, void* d_ws, size_t ws_size,
                              hipStream_t stream) {
    const float* x0 = (const float*)d_in[0];
    const float* ts = (const float*)d_in[1];
    float* out = (float*)d_out;
    int B = in_sizes[0] / 3;
    int T = in_sizes[1];
    int threads = 256;
    int pairs = B / 2;
    int blocks = (pairs + threads - 1) / threads;
    lorenz_lya_kernel<<<blocks, threads, 0, stream>>>(x0, ts, out, B, T);
}